// Round 3
// baseline (210.959 us; speedup 1.0000x reference)
//
#include <hip/hip_runtime.h>

// Problem constants
#define T_ 128
#define B_ 64
#define NH_ 64
#define NC_ 10

__device__ __forceinline__ float sigmoid_f(float x) {
    return 1.0f / (1.0f + __expf(-x));
}
__device__ __forceinline__ float tanh_f(float x) {
    return 1.0f - 2.0f / (1.0f + __expf(2.0f * x));
}
// Broadcast lane k's value to all lanes (VALU readlane -> SGPR, no LDS).
__device__ __forceinline__ float readlane_f(float v, int lane) {
    return __int_as_float(__builtin_amdgcn_readlane(__float_as_int(v), lane));
}

// ---------------------------------------------------------------------------
// Kernel 1: per-frame 3x3 VALID conv -> sigmoid(logit-thr) -> spatial mean.
// Thread = one 16-wide output run: 15 ds_read_b128 (vs 144 b32 before),
// register-reused 3x3 window. grid = 8192, 256 threads.
// ---------------------------------------------------------------------------
#define IMP 68  // padded LDS row pitch (floats): 68*4 B is 16B-aligned
__global__ __launch_bounds__(256) void conv_feat(const float* __restrict__ img,
                                                 const float* __restrict__ cw,
                                                 const float* __restrict__ cb,
                                                 const float* __restrict__ thr,
                                                 float* __restrict__ feat) {
    __shared__ __align__(16) float im[64 * IMP];
    __shared__ float wsum[4];
    const int tid = threadIdx.x;
    const float* src = img + (size_t)blockIdx.x * 4096;
#pragma unroll
    for (int i = 0; i < 4; i++) {
        const int idx = i * 256 + tid;       // float4 index 0..1023
        const int row = idx >> 4, c4 = idx & 15;
        *(float4*)&im[row * IMP + c4 * 4] = *(const float4*)&src[idx * 4];
    }
    const float w0 = cw[0], w1 = cw[1], w2 = cw[2], w3 = cw[3], w4 = cw[4],
                w5 = cw[5], w6 = cw[6], w7 = cw[7], w8 = cw[8];
    const float bias = cb[0] - thr[0];
    __syncthreads();

    const int r  = tid >> 2;          // output row 0..63 (62,63 idle)
    const int c0 = (tid & 3) * 16;    // output col base
    float sum = 0.0f;
    if (r < 62) {
        const int ncols = (c0 == 48) ? 14 : 16;
        float acc[16];
#pragma unroll
        for (int x = 0; x < 16; x++) acc[x] = bias;
#pragma unroll
        for (int dr = 0; dr < 3; dr++) {
            float rb[20];
#pragma unroll
            for (int j = 0; j < 5; j++) {
                float4 v = *(const float4*)&im[(r + dr) * IMP + c0 + j * 4];
                rb[j * 4 + 0] = v.x; rb[j * 4 + 1] = v.y;
                rb[j * 4 + 2] = v.z; rb[j * 4 + 3] = v.w;
            }
            const float k0 = (dr == 0) ? w0 : (dr == 1) ? w3 : w6;
            const float k1 = (dr == 0) ? w1 : (dr == 1) ? w4 : w7;
            const float k2 = (dr == 0) ? w2 : (dr == 1) ? w5 : w8;
#pragma unroll
            for (int x = 0; x < 16; x++) {
                acc[x] = fmaf(rb[x], k0, acc[x]);
                acc[x] = fmaf(rb[x + 1], k1, acc[x]);
                acc[x] = fmaf(rb[x + 2], k2, acc[x]);
            }
        }
#pragma unroll
        for (int x = 0; x < 16; x++)
            if (x < ncols) sum += sigmoid_f(acc[x]);
    }
#pragma unroll
    for (int off = 32; off >= 1; off >>= 1) sum += __shfl_down(sum, off, 64);
    const int wv = tid >> 6, ln = tid & 63;
    if (ln == 0) wsum[wv] = sum;
    __syncthreads();
    if (tid == 0)
        feat[blockIdx.x] = (wsum[0] + wsum[1] + wsum[2] + wsum[3]) * (1.0f / 3844.0f);
}

// ---------------------------------------------------------------------------
// Kernel 2: fold fc+lw per gate: A = lw@fc_w[:,1:], v = lw@fc_w[:,0],
// c = lw@fc_b + lb.  grid = 4 (one block per gate), 256 threads.
// ---------------------------------------------------------------------------
struct FuseArgs {
    const float* fcw[4];
    const float* fcb[4];
    const float* lw[4];
    const float* lb[4];
};

__global__ __launch_bounds__(256) void fuse_kernel(FuseArgs a, float* __restrict__ Aall,
                                                   float* __restrict__ Vall,
                                                   float* __restrict__ Call) {
    const int g = blockIdx.x;
    const float* fcw = a.fcw[g];  // [64][65]
    const float* fcb = a.fcb[g];  // [64]
    const float* lw  = a.lw[g];   // [64][64]
    const float* lb  = a.lb[g];   // [64]
    __shared__ float fcs[64 * 65];
    __shared__ float fbs[64];
    for (int i = threadIdx.x; i < 64 * 65; i += 256) fcs[i] = fcw[i];
    if (threadIdx.x < 64) fbs[threadIdx.x] = fcb[threadIdx.x];
    __syncthreads();

    const int n = threadIdx.x >> 2;
    const int j0 = (threadIdx.x & 3) * 16;
    float lrow[64];
#pragma unroll
    for (int k = 0; k < 64; k++) lrow[k] = lw[n * 64 + k];

    for (int j = j0; j < j0 + 16; j++) {
        float s = 0.0f;
#pragma unroll
        for (int k = 0; k < 64; k++) s = fmaf(lrow[k], fcs[k * 65 + j + 1], s);
        Aall[(g * 64 + n) * 64 + j] = s;
    }
    if ((threadIdx.x & 3) == 0) {
        float sv = 0.0f, sc = 0.0f;
#pragma unroll
        for (int k = 0; k < 64; k++) {
            sv = fmaf(lrow[k], fcs[k * 65], sv);
            sc = fmaf(lrow[k], fbs[k], sc);
        }
        Vall[g * 64 + n] = sv;
        Call[g * 64 + n] = sc + lb[n];
    }
}

// ---------------------------------------------------------------------------
// Kernel 3: recurrence + fused classifier. One block per batch row (64),
// 4 waves = 4 gates, lane n = hidden unit n. All matvec broadcasts via
// v_readlane (register-only); LDS touched once per step (acts exchange)
// with a single __syncthreads. h and cx live in registers, replicated
// across waves via redundant (bitwise-identical) cell updates.
// ---------------------------------------------------------------------------
__global__ __launch_bounds__(256, 1) void recur(
    const float* __restrict__ feat, const float* __restrict__ Aall,
    const float* __restrict__ Vall, const float* __restrict__ Call,
    const float* __restrict__ ew_f, const float* __restrict__ eb_f,
    const float* __restrict__ ew_i, const float* __restrict__ eb_i,
    const float* __restrict__ ew_u, const float* __restrict__ eb_u,
    const float* __restrict__ ew_o, const float* __restrict__ eb_o,
    const float* __restrict__ cls_w, const float* __restrict__ cls_b,
    float* __restrict__ out) {
    const int b = blockIdx.x;
    const int tid = threadIdx.x;
    const int g = tid >> 6, n = tid & 63;
    const float* ew  = (g == 0) ? ew_f : (g == 1) ? ew_i : (g == 2) ? ew_u : ew_o;
    const float* ebp = (g == 0) ? eb_f : (g == 1) ? eb_i : (g == 2) ? eb_u : eb_o;

    float W1[64], W2[64];
#pragma unroll
    for (int k4 = 0; k4 < 16; k4++) {
        float4 av = *(const float4*)&Aall[tid * 64 + k4 * 4];
        W1[k4 * 4 + 0] = av.x; W1[k4 * 4 + 1] = av.y;
        W1[k4 * 4 + 2] = av.z; W1[k4 * 4 + 3] = av.w;
        float4 ev = *(const float4*)&ew[n * 64 + k4 * 4];
        W2[k4 * 4 + 0] = ev.x; W2[k4 * 4 + 1] = ev.y;
        W2[k4 * 4 + 2] = ev.z; W2[k4 * 4 + 3] = ev.w;
    }
    const float vj = Vall[tid], cj = Call[tid], ebj = ebp[n];

    __shared__ __align__(16) float acts[2][4][64];  // double-buffered exchange
    __shared__ float xts[T_];
    __shared__ float hist[T_ * 65];                 // padded h history (33 KB)
    __shared__ float cwts[NC_ * 65 + NC_];          // padded cls_w + cls_b

    for (int i = tid; i < T_; i += 256) xts[i] = feat[b * T_ + i];
    for (int i = tid; i < NC_ * 64; i += 256) {
        int c = i >> 6, k = i & 63;
        cwts[c * 65 + k] = cls_w[i];
    }
    if (tid < NC_) cwts[NC_ * 65 + tid] = cls_b[tid];
    float h_reg = 0.0f, cx = 0.0f;
    __syncthreads();

    for (int t = 0; t < T_; t++) {
        const float xt = xts[t];  // wave-uniform broadcast read, issued early

        // stage 1: q = tanh(xt*v + h @ A^T + c) — h broadcast via readlane
        float a0 = 0, a1 = 0, a2 = 0, a3 = 0;
#pragma unroll
        for (int k4 = 0; k4 < 16; k4++) {
            const int k = k4 * 4;
            a0 = fmaf(W1[k + 0], readlane_f(h_reg, k + 0), a0);
            a1 = fmaf(W1[k + 1], readlane_f(h_reg, k + 1), a1);
            a2 = fmaf(W1[k + 2], readlane_f(h_reg, k + 2), a2);
            a3 = fmaf(W1[k + 3], readlane_f(h_reg, k + 3), a3);
        }
        const float q = tanh_f(fmaf(xt, vj, cj) + ((a0 + a1) + (a2 + a3)));

        // stage 2: z = q * sigmoid(q @ ew^T + eb) — q broadcast via readlane
        float s0 = 0, s1 = 0, s2 = 0, s3 = 0;
#pragma unroll
        for (int k4 = 0; k4 < 16; k4++) {
            const int k = k4 * 4;
            s0 = fmaf(W2[k + 0], readlane_f(q, k + 0), s0);
            s1 = fmaf(W2[k + 1], readlane_f(q, k + 1), s1);
            s2 = fmaf(W2[k + 2], readlane_f(q, k + 2), s2);
            s3 = fmaf(W2[k + 3], readlane_f(q, k + 3), s3);
        }
        const float z = q * sigmoid_f(((s0 + s1) + (s2 + s3)) + ebj);
        const float act = (g == 2) ? tanh_f(z) : sigmoid_f(z);

        // the ONLY LDS+sync point: exchange the 4 gate activations
        acts[t & 1][g][n] = act;
        __syncthreads();
        const float ff = acts[t & 1][0][n];
        const float ii = acts[t & 1][1][n];
        const float uu = acts[t & 1][2][n];
        const float oo = acts[t & 1][3][n];

        // cell update — redundantly on all 4 waves (bitwise identical)
        cx = fmaf(ff, cx, ii * uu);
        h_reg = oo * tanh_f(cx);
        if (g == 0) hist[t * 65 + n] = h_reg;  // flushed by next barrier
    }
    __syncthreads();

    // fused classifier: T_*NC_ = 1280 outputs
#pragma unroll
    for (int j = 0; j < 5; j++) {
        const int o = j * 256 + tid;
        const int r = o / 10;
        const int c = o - r * 10;
        float s = cwts[NC_ * 65 + c];
#pragma unroll 16
        for (int k = 0; k < 64; k++) s = fmaf(hist[r * 65 + k], cwts[c * 65 + k], s);
        out[((size_t)r * B_ + b) * NC_ + c] = s;
    }
}

// ---------------------------------------------------------------------------
extern "C" void kernel_launch(void* const* d_in, const int* in_sizes, int n_in,
                              void* d_out, int out_size, void* d_ws, size_t ws_size,
                              hipStream_t stream) {
    const float* images = (const float*)d_in[0];
    const float* thr    = (const float*)d_in[1];
    const float* convw  = (const float*)d_in[2];
    const float* convb  = (const float*)d_in[3];
    const float* fcw[4]; const float* fcb[4]; const float* lw[4]; const float* lb[4];
    const float* ew[4];  const float* eb[4];
    for (int g = 0; g < 4; g++) {
        int base = 4 + g * 6;
        fcw[g] = (const float*)d_in[base + 0];
        fcb[g] = (const float*)d_in[base + 1];
        lw[g]  = (const float*)d_in[base + 2];
        lb[g]  = (const float*)d_in[base + 3];
        ew[g]  = (const float*)d_in[base + 4];
        eb[g]  = (const float*)d_in[base + 5];
    }
    const float* clsw = (const float*)d_in[28];
    const float* clsb = (const float*)d_in[29];

    float* ws   = (float*)d_ws;
    float* feat = ws;            // 8192 floats
    float* Aall = ws + 8192;     // 16384 floats
    float* Vall = ws + 24576;    // 256
    float* Call = ws + 24832;    // 256

    conv_feat<<<8192, 256, 0, stream>>>(images, convw, convb, thr, feat);

    FuseArgs fa;
    for (int g = 0; g < 4; g++) {
        fa.fcw[g] = fcw[g]; fa.fcb[g] = fcb[g];
        fa.lw[g] = lw[g];   fa.lb[g] = lb[g];
    }
    fuse_kernel<<<4, 256, 0, stream>>>(fa, Aall, Vall, Call);

    recur<<<B_, 256, 0, stream>>>(feat, Aall, Vall, Call,
                                  ew[0], eb[0], ew[1], eb[1],
                                  ew[2], eb[2], ew[3], eb[3],
                                  clsw, clsb, (float*)d_out);
}

// Round 4
// 192.644 us; speedup vs baseline: 1.0951x; 1.0951x over previous
//
#include <hip/hip_runtime.h>

// Problem constants
#define T_ 128
#define B_ 64
#define NH_ 64
#define NC_ 10

__device__ __forceinline__ float sigmoid_f(float x) {
    return 1.0f / (1.0f + __expf(-x));
}
__device__ __forceinline__ float tanh_f(float x) {
    return 1.0f - 2.0f / (1.0f + __expf(2.0f * x));
}

// ---------------------------------------------------------------------------
// Kernel 1: per-frame 3x3 VALID conv -> sigmoid(logit-thr) -> spatial mean.
// grid = 8192, 256 threads. (unchanged from round 3)
// ---------------------------------------------------------------------------
#define IMP 68
__global__ __launch_bounds__(256) void conv_feat(const float* __restrict__ img,
                                                 const float* __restrict__ cw,
                                                 const float* __restrict__ cb,
                                                 const float* __restrict__ thr,
                                                 float* __restrict__ feat) {
    __shared__ __align__(16) float im[64 * IMP];
    __shared__ float wsum[4];
    const int tid = threadIdx.x;
    const float* src = img + (size_t)blockIdx.x * 4096;
#pragma unroll
    for (int i = 0; i < 4; i++) {
        const int idx = i * 256 + tid;
        const int row = idx >> 4, c4 = idx & 15;
        *(float4*)&im[row * IMP + c4 * 4] = *(const float4*)&src[idx * 4];
    }
    const float w0 = cw[0], w1 = cw[1], w2 = cw[2], w3 = cw[3], w4 = cw[4],
                w5 = cw[5], w6 = cw[6], w7 = cw[7], w8 = cw[8];
    const float bias = cb[0] - thr[0];
    __syncthreads();

    const int r  = tid >> 2;
    const int c0 = (tid & 3) * 16;
    float sum = 0.0f;
    if (r < 62) {
        const int ncols = (c0 == 48) ? 14 : 16;
        float acc[16];
#pragma unroll
        for (int x = 0; x < 16; x++) acc[x] = bias;
#pragma unroll
        for (int dr = 0; dr < 3; dr++) {
            float rb[20];
#pragma unroll
            for (int j = 0; j < 5; j++) {
                float4 v = *(const float4*)&im[(r + dr) * IMP + c0 + j * 4];
                rb[j * 4 + 0] = v.x; rb[j * 4 + 1] = v.y;
                rb[j * 4 + 2] = v.z; rb[j * 4 + 3] = v.w;
            }
            const float k0 = (dr == 0) ? w0 : (dr == 1) ? w3 : w6;
            const float k1 = (dr == 0) ? w1 : (dr == 1) ? w4 : w7;
            const float k2 = (dr == 0) ? w2 : (dr == 1) ? w5 : w8;
#pragma unroll
            for (int x = 0; x < 16; x++) {
                acc[x] = fmaf(rb[x], k0, acc[x]);
                acc[x] = fmaf(rb[x + 1], k1, acc[x]);
                acc[x] = fmaf(rb[x + 2], k2, acc[x]);
            }
        }
#pragma unroll
        for (int x = 0; x < 16; x++)
            if (x < ncols) sum += sigmoid_f(acc[x]);
    }
#pragma unroll
    for (int off = 32; off >= 1; off >>= 1) sum += __shfl_down(sum, off, 64);
    const int wv = tid >> 6, ln = tid & 63;
    if (ln == 0) wsum[wv] = sum;
    __syncthreads();
    if (tid == 0)
        feat[blockIdx.x] = (wsum[0] + wsum[1] + wsum[2] + wsum[3]) * (1.0f / 3844.0f);
}

// ---------------------------------------------------------------------------
// Kernel 2: fold fc+lw per gate (unchanged). grid = 4, 256 threads.
// ---------------------------------------------------------------------------
struct FuseArgs {
    const float* fcw[4];
    const float* fcb[4];
    const float* lw[4];
    const float* lb[4];
};

__global__ __launch_bounds__(256) void fuse_kernel(FuseArgs a, float* __restrict__ Aall,
                                                   float* __restrict__ Vall,
                                                   float* __restrict__ Call) {
    const int g = blockIdx.x;
    const float* fcw = a.fcw[g];
    const float* fcb = a.fcb[g];
    const float* lw  = a.lw[g];
    const float* lb  = a.lb[g];
    __shared__ float fcs[64 * 65];
    __shared__ float fbs[64];
    for (int i = threadIdx.x; i < 64 * 65; i += 256) fcs[i] = fcw[i];
    if (threadIdx.x < 64) fbs[threadIdx.x] = fcb[threadIdx.x];
    __syncthreads();

    const int n = threadIdx.x >> 2;
    const int j0 = (threadIdx.x & 3) * 16;
    float lrow[64];
#pragma unroll
    for (int k = 0; k < 64; k++) lrow[k] = lw[n * 64 + k];

    for (int j = j0; j < j0 + 16; j++) {
        float s = 0.0f;
#pragma unroll
        for (int k = 0; k < 64; k++) s = fmaf(lrow[k], fcs[k * 65 + j + 1], s);
        Aall[(g * 64 + n) * 64 + j] = s;
    }
    if ((threadIdx.x & 3) == 0) {
        float sv = 0.0f, sc = 0.0f;
#pragma unroll
        for (int k = 0; k < 64; k++) {
            sv = fmaf(lrow[k], fcs[k * 65], sv);
            sc = fmaf(lrow[k], fbs[k], sc);
        }
        Vall[g * 64 + n] = sv;
        Call[g * 64 + n] = sc + lb[n];
    }
}

// ---------------------------------------------------------------------------
// Kernel 3: recurrence + fused classifier. TWO batch rows per block
// (512 threads = 8 waves -> 2 waves/SIMD for latency hiding). Within a row:
// wave = gate, lane = hidden unit. Weights in 32 NAMED float4 registers
// (defeats the array->scratch demotion seen as VGPR_Count=72..84).
// R1-proven 3-barrier schedule, h-history in LDS, classifier fused.
// ---------------------------------------------------------------------------
#define S1STEP(i) { float4 h = hp[i]; \
    a0 = fmaf(w1_##i.x, h.x, a0); a1 = fmaf(w1_##i.y, h.y, a1); \
    a2 = fmaf(w1_##i.z, h.z, a2); a3 = fmaf(w1_##i.w, h.w, a3); }
#define S2STEP(i) { float4 qv = qp[i]; \
    s0 = fmaf(w2_##i.x, qv.x, s0); s1 = fmaf(w2_##i.y, qv.y, s1); \
    s2 = fmaf(w2_##i.z, qv.z, s2); s3 = fmaf(w2_##i.w, qv.w, s3); }

__global__ __launch_bounds__(512, 2) void recur2(
    const float* __restrict__ feat, const float* __restrict__ Aall,
    const float* __restrict__ Vall, const float* __restrict__ Call,
    const float* __restrict__ ew_f, const float* __restrict__ eb_f,
    const float* __restrict__ ew_i, const float* __restrict__ eb_i,
    const float* __restrict__ ew_u, const float* __restrict__ eb_u,
    const float* __restrict__ ew_o, const float* __restrict__ eb_o,
    const float* __restrict__ cls_w, const float* __restrict__ cls_b,
    float* __restrict__ out) {
    const int row = threadIdx.x >> 8;        // 0 or 1
    const int tid = threadIdx.x & 255;       // within-row thread
    const int b = (blockIdx.x << 1) | row;   // batch row
    const int g = tid >> 6, n = tid & 63;
    const float* ew  = (g == 0) ? ew_f : (g == 1) ? ew_i : (g == 2) ? ew_u : ew_o;
    const float* ebp = (g == 0) ? eb_f : (g == 1) ? eb_i : (g == 2) ? eb_u : eb_o;

    // --- weights in NAMED registers (no arrays -> no scratch demotion) ---
    const float4* ap = (const float4*)&Aall[tid * 64];
    const float4* ep = (const float4*)&ew[n * 64];
    const float4 w1_0  = ap[0],  w1_1  = ap[1],  w1_2  = ap[2],  w1_3  = ap[3];
    const float4 w1_4  = ap[4],  w1_5  = ap[5],  w1_6  = ap[6],  w1_7  = ap[7];
    const float4 w1_8  = ap[8],  w1_9  = ap[9],  w1_10 = ap[10], w1_11 = ap[11];
    const float4 w1_12 = ap[12], w1_13 = ap[13], w1_14 = ap[14], w1_15 = ap[15];
    const float4 w2_0  = ep[0],  w2_1  = ep[1],  w2_2  = ep[2],  w2_3  = ep[3];
    const float4 w2_4  = ep[4],  w2_5  = ep[5],  w2_6  = ep[6],  w2_7  = ep[7];
    const float4 w2_8  = ep[8],  w2_9  = ep[9],  w2_10 = ep[10], w2_11 = ep[11];
    const float4 w2_12 = ep[12], w2_13 = ep[13], w2_14 = ep[14], w2_15 = ep[15];
    const float vj = Vall[tid], cj = Call[tid], ebj = ebp[n];

    __shared__ __align__(16) float hxs[2][64];
    __shared__ __align__(16) float qs[2][256];
    __shared__ __align__(16) float acts[2][256];
    __shared__ __align__(16) float xts[2][T_];
    __shared__ __align__(16) float hist[2][T_ * 65];   // 66.6 KB
    __shared__ float cwts[NC_ * 65 + NC_];

    for (int i = tid; i < T_; i += 256) xts[row][i] = feat[b * T_ + i];
    for (int i = threadIdx.x; i < NC_ * 64; i += 512) {
        int c = i >> 6, k = i & 63;
        cwts[c * 65 + k] = cls_w[i];
    }
    if (threadIdx.x < NC_) cwts[NC_ * 65 + threadIdx.x] = cls_b[threadIdx.x];
    if (tid < 64) hxs[row][tid] = 0.0f;
    float cx = 0.0f;
    __syncthreads();

    for (int t = 0; t < T_; t++) {
        const float xt = xts[row][t];

        // stage 1: q = tanh(xt*v + h @ A^T + c)
        float a0 = 0, a1 = 0, a2 = 0, a3 = 0;
        {
            const float4* hp = (const float4*)&hxs[row][0];
            S1STEP(0)  S1STEP(1)  S1STEP(2)  S1STEP(3)
            S1STEP(4)  S1STEP(5)  S1STEP(6)  S1STEP(7)
            S1STEP(8)  S1STEP(9)  S1STEP(10) S1STEP(11)
            S1STEP(12) S1STEP(13) S1STEP(14) S1STEP(15)
        }
        const float q = tanh_f(fmaf(xt, vj, cj) + ((a0 + a1) + (a2 + a3)));
        qs[row][tid] = q;
        __syncthreads();

        // stage 2: z = q * sigmoid(q @ ew^T + eb); gate activation
        float s0 = 0, s1 = 0, s2 = 0, s3 = 0;
        {
            const float4* qp = (const float4*)&qs[row][g << 6];
            S2STEP(0)  S2STEP(1)  S2STEP(2)  S2STEP(3)
            S2STEP(4)  S2STEP(5)  S2STEP(6)  S2STEP(7)
            S2STEP(8)  S2STEP(9)  S2STEP(10) S2STEP(11)
            S2STEP(12) S2STEP(13) S2STEP(14) S2STEP(15)
        }
        const float z = q * sigmoid_f(((s0 + s1) + (s2 + s3)) + ebj);
        acts[row][tid] = (g == 2) ? tanh_f(z) : sigmoid_f(z);
        __syncthreads();

        // cell update by lanes 0..63 of wave 0 (per row)
        if (tid < 64) {
            const float ff = acts[row][tid], ii = acts[row][64 + tid],
                        uu = acts[row][128 + tid], oo = acts[row][192 + tid];
            cx = fmaf(ff, cx, ii * uu);
            const float h = oo * tanh_f(cx);
            hxs[row][tid] = h;
            hist[row][t * 65 + tid] = h;
        }
        __syncthreads();
    }

    // fused classifier: per row T_*NC_ = 1280 outputs over 256 threads
#pragma unroll
    for (int j = 0; j < 5; j++) {
        const int o = j * 256 + tid;
        const int r = o / 10;
        const int c = o - r * 10;
        float s = cwts[NC_ * 65 + c];
#pragma unroll 16
        for (int k = 0; k < 64; k++) s = fmaf(hist[row][r * 65 + k], cwts[c * 65 + k], s);
        out[((size_t)r * B_ + b) * NC_ + c] = s;
    }
}

// ---------------------------------------------------------------------------
extern "C" void kernel_launch(void* const* d_in, const int* in_sizes, int n_in,
                              void* d_out, int out_size, void* d_ws, size_t ws_size,
                              hipStream_t stream) {
    const float* images = (const float*)d_in[0];
    const float* thr    = (const float*)d_in[1];
    const float* convw  = (const float*)d_in[2];
    const float* convb  = (const float*)d_in[3];
    const float* fcw[4]; const float* fcb[4]; const float* lw[4]; const float* lb[4];
    const float* ew[4];  const float* eb[4];
    for (int g = 0; g < 4; g++) {
        int base = 4 + g * 6;
        fcw[g] = (const float*)d_in[base + 0];
        fcb[g] = (const float*)d_in[base + 1];
        lw[g]  = (const float*)d_in[base + 2];
        lb[g]  = (const float*)d_in[base + 3];
        ew[g]  = (const float*)d_in[base + 4];
        eb[g]  = (const float*)d_in[base + 5];
    }
    const float* clsw = (const float*)d_in[28];
    const float* clsb = (const float*)d_in[29];

    float* ws   = (float*)d_ws;
    float* feat = ws;            // 8192 floats
    float* Aall = ws + 8192;     // 16384 floats
    float* Vall = ws + 24576;    // 256
    float* Call = ws + 24832;    // 256

    conv_feat<<<8192, 256, 0, stream>>>(images, convw, convb, thr, feat);

    FuseArgs fa;
    for (int g = 0; g < 4; g++) {
        fa.fcw[g] = fcw[g]; fa.fcb[g] = fcb[g];
        fa.lw[g] = lw[g];   fa.lb[g] = lb[g];
    }
    fuse_kernel<<<4, 256, 0, stream>>>(fa, Aall, Vall, Call);

    recur2<<<B_ / 2, 512, 0, stream>>>(feat, Aall, Vall, Call,
                                       ew[0], eb[0], ew[1], eb[1],
                                       ew[2], eb[2], ew[3], eb[3],
                                       clsw, clsb, (float*)d_out);
}